// Round 5
// baseline (500.717 us; speedup 1.0000x reference)
//
#include <hip/hip_runtime.h>

#define T_TOK 8192
#define DIMSZ 512
#define HIDSZ 1536
#define SHIDSZ 3072
#define NE 8

typedef __attribute__((ext_vector_type(4))) float f32x4;
typedef __attribute__((ext_vector_type(8))) short s16x8;

#define SBAR() __builtin_amdgcn_s_barrier()

__device__ __forceinline__ unsigned short f2bf(float f) {
  unsigned int u = __float_as_uint(f);
  u += 0x7fff + ((u >> 16) & 1);
  return (unsigned short)(u >> 16);
}

__device__ __forceinline__ void async16(void* lds, const void* g) {
  __builtin_amdgcn_global_load_lds((const __attribute__((address_space(1))) void*)g,
                                   (__attribute__((address_space(3))) void*)lds,
                                   16, 0, 0);
}

// ---------------- convert fp32 -> bf16 (vectorized) ----------------
__global__ void cvt_bf16(const float* __restrict__ s, unsigned short* __restrict__ d, int n4) {
  int i = blockIdx.x * blockDim.x + threadIdx.x;
  if (i < n4) {
    float4 v = ((const float4*)s)[i];
    ushort4 o;
    o.x = f2bf(v.x); o.y = f2bf(v.y); o.z = f2bf(v.z); o.w = f2bf(v.w);
    ((ushort4*)d)[i] = o;
  }
}

// ---------------- gate: logits, softmax, top-2, block-aggregated counts ------
#define GATE_BLOCKS 256
#define GATE_TPB (T_TOK / GATE_BLOCKS)
#define GATE_TPW (GATE_TPB / 4)

__global__ __launch_bounds__(256) void gate_kernel(
    const float* __restrict__ x, const float* __restrict__ gw,
    float* __restrict__ tw, int* __restrict__ ti, int* __restrict__ cnt) {
  __shared__ int lcnt[NE];
  const int tid = threadIdx.x;
  if (tid < NE) lcnt[tid] = 0;
  __syncthreads();
  const int w = tid >> 6, l = tid & 63;

  float gv[NE][8];
  const float* gbase = gw + l * 8;
#pragma unroll
  for (int e = 0; e < NE; ++e)
#pragma unroll
    for (int j = 0; j < 8; ++j) gv[e][j] = gbase[e * DIMSZ + j];

  const int tok0 = blockIdx.x * GATE_TPB + w * GATE_TPW;
  for (int it = 0; it < GATE_TPW; ++it) {
    const int t = tok0 + it;
    const float* xr = x + (size_t)t * DIMSZ + l * 8;
    float xv[8];
#pragma unroll
    for (int j = 0; j < 8; ++j) xv[j] = xr[j];
    float p[NE];
#pragma unroll
    for (int e = 0; e < NE; ++e) {
      float s = 0.f;
#pragma unroll
      for (int j = 0; j < 8; ++j) s = fmaf(xv[j], gv[e][j], s);
      p[e] = s;
    }
#pragma unroll
    for (int e = 0; e < NE; ++e) {
      float v = p[e];
#pragma unroll
      for (int off = 32; off > 0; off >>= 1) v += __shfl_xor(v, off);
      p[e] = v;
    }
    float m = p[0];
#pragma unroll
    for (int e = 1; e < NE; ++e) m = fmaxf(m, p[e]);
    float ex[NE], s = 0.f;
#pragma unroll
    for (int e = 0; e < NE; ++e) { ex[e] = __expf(p[e] - m); s += ex[e]; }
    float inv = 1.f / s;
    int e0 = 0; float v0 = p[0];
#pragma unroll
    for (int e = 1; e < NE; ++e) if (p[e] > v0) { v0 = p[e]; e0 = e; }
    int e1 = -1; float v1 = -3.4e38f;
#pragma unroll
    for (int e = 0; e < NE; ++e) if (e != e0 && p[e] > v1) { v1 = p[e]; e1 = e; }
    if (l == 0) {
      ti[2 * t] = e0;     tw[2 * t] = ex[e0] * inv;
      ti[2 * t + 1] = e1; tw[2 * t + 1] = ex[e1] * inv;
      atomicAdd(&lcnt[e0], 1);
      atomicAdd(&lcnt[e1], 1);
    }
  }
  __syncthreads();
  if (tid < NE) atomicAdd(&cnt[tid], lcnt[tid]);
}

// ---------------- exclusive scan over 8 expert counts ----------------
__global__ void scan_kernel(const int* __restrict__ cnt, int* __restrict__ base,
                            int* __restrict__ cursor) {
  if (threadIdx.x == 0 && blockIdx.x == 0) {
    int r = 0;
    for (int e = 0; e < NE; ++e) { base[e] = r; cursor[e] = r; r += cnt[e]; }
  }
}

// ---------------- scatter (block-aggregated) ----------------
__global__ __launch_bounds__(256) void scatter_kernel(
    const int* __restrict__ ti, int* __restrict__ cursor,
    int* __restrict__ tok, int* __restrict__ dst) {
  __shared__ int lcnt[NE], gbase[NE];
  const int tid = threadIdx.x;
  if (tid < NE) lcnt[tid] = 0;
  __syncthreads();
  const int t = blockIdx.x * 256 + tid;
  const int e0 = ti[2 * t], e1 = ti[2 * t + 1];
  const int p0 = atomicAdd(&lcnt[e0], 1);
  const int p1 = atomicAdd(&lcnt[e1], 1);
  __syncthreads();
  if (tid < NE) gbase[tid] = atomicAdd(&cursor[tid], lcnt[tid]);
  __syncthreads();
  const int i0 = gbase[e0] + p0, i1 = gbase[e1] + p1;
  tok[i0] = t; dst[i0] = 2 * t;
  tok[i1] = t; dst[i1] = 2 * t + 1;
}

// ---------------- gather bf16 x rows into bucket order ----------------
__global__ void gather_kernel(const unsigned short* __restrict__ xb,
                              const int* __restrict__ tok,
                              unsigned short* __restrict__ xg) {
  int i = blockIdx.x * blockDim.x + threadIdx.x;
  int entry = i >> 6, l = i & 63;
  int t = tok[entry];
  ((uint4*)xg)[entry * 64 + l] = ((const uint4*)xb)[t * 64 + l];
}

// =====================================================================
// GEMMs: BK=64 rows (128B) with XOR chunk-swizzle (T2, rule-21) +
// 2-phase double-buffered pipeline (T3-minimum): stage tile t+1 into
// buf^1 BEFORE computing tile t; counted vmcnt (8/6, never 0 mid-loop);
// raw s_barrier (no compiler vmcnt(0) drain).
//   iter t: [stage t+1 -> buf^1] [vmcnt(N)] [SBAR] [compute buf] [SBAR]
// Race-safety: ds_reads of buf are consumed by MFMAs (compiler lgkmcnt)
// before SBAR#2; stage into buf happens only after SBAR#2.
// =====================================================================

// ---------------- GEMM1: g = silu(A@W1^T) * (A@W3^T), bf16 out ----------------
// Tile 128M x 64N, BK=64, 4 waves (2Mx2N, per-wave 64x32 dual). LDS 64KB dbuf.
template <bool ROUTED>
__global__ __launch_bounds__(256, 2) void gemm1_kernel(
    const unsigned short* __restrict__ A0, const unsigned short* __restrict__ W1,
    const unsigned short* __restrict__ W3, unsigned short* __restrict__ G,
    const int* __restrict__ cnt, const int* __restrict__ base,
    int K, int N, int mtPerE) {
  int e, mt, cntE, rowbase;
  if constexpr (ROUTED) {
    e = blockIdx.x / mtPerE; mt = blockIdx.x % mtPerE;
    cntE = cnt[e];
    if (mt * 128 >= cntE) return;
    rowbase = base[e];
  } else {
    e = 0; mt = blockIdx.x; cntE = T_TOK; rowbase = 0;
  }
  const int m0 = mt * 128;
  const int n0 = blockIdx.y * 64;
  const unsigned short* A = A0 + (size_t)rowbase * K;
  const unsigned short* B1 = W1 + (size_t)e * N * K + (size_t)n0 * K;
  const unsigned short* B3 = W3 + (size_t)e * N * K + (size_t)n0 * K;

  __shared__ __align__(16) unsigned short As[2 * 128 * 64];
  __shared__ __align__(16) unsigned short B1s[2 * 64 * 64];
  __shared__ __align__(16) unsigned short B3s[2 * 64 * 64];

  const int tid = threadIdx.x;
  const int w = tid >> 6, lane = tid & 63;
  const int wr = w >> 1, wc = w & 1;
  const int lhi = lane >> 4, llo = lane & 15;

  // staging: pre-swizzled global chunk sources + linear LDS dest offsets
  const unsigned short* aSrc[4];
  int aDst[4];
#pragma unroll
  for (int i = 0; i < 4; ++i) {
    int L = i * 256 + tid, row = L >> 3, c = L & 7, sc = c ^ (row & 7);
    int ar = ROUTED ? min(m0 + row, cntE - 1) : (m0 + row);
    aSrc[i] = A + (size_t)ar * K + sc * 8;
    aDst[i] = (i * 256 + (tid & ~63)) * 8;
  }
  const unsigned short *b1Src[2], *b3Src[2];
  int bDst[2];
#pragma unroll
  for (int i = 0; i < 2; ++i) {
    int L = i * 256 + tid, row = L >> 3, c = L & 7, sc = c ^ (row & 7);
    b1Src[i] = B1 + (size_t)row * K + sc * 8;
    b3Src[i] = B3 + (size_t)row * K + sc * 8;
    bDst[i] = (i * 256 + (tid & ~63)) * 8;
  }

  // swizzled ds_read offsets (ushort units, within one buffer)
  int aOff[4][2], bOff[2][2];
#pragma unroll
  for (int m = 0; m < 4; ++m) {
    int r = wr * 64 + m * 16 + llo;
#pragma unroll
    for (int s = 0; s < 2; ++s)
      aOff[m][s] = r * 64 + (((lhi + 4 * s) ^ (r & 7)) * 8);
  }
#pragma unroll
  for (int n = 0; n < 2; ++n) {
    int r = wc * 32 + n * 16 + llo;
#pragma unroll
    for (int s = 0; s < 2; ++s)
      bOff[n][s] = r * 64 + (((lhi + 4 * s) ^ (r & 7)) * 8);
  }

  f32x4 acc1[4][2], acc3[4][2];
#pragma unroll
  for (int m = 0; m < 4; ++m)
#pragma unroll
    for (int n = 0; n < 2; ++n) {
      acc1[m][n] = f32x4{0.f, 0.f, 0.f, 0.f};
      acc3[m][n] = f32x4{0.f, 0.f, 0.f, 0.f};
    }

  const int nt = K >> 6;
  int cur = 0;
  // prologue: stage tile 0 into buf 0
#pragma unroll
  for (int i = 0; i < 4; ++i) async16(&As[aDst[i]], aSrc[i]);
#pragma unroll
  for (int i = 0; i < 2; ++i) {
    async16(&B1s[bDst[i]], b1Src[i]);
    async16(&B3s[bDst[i]], b3Src[i]);
  }

  for (int t = 0; t < nt; ++t) {
    const bool more = (t + 1) < nt;
    if (more) {
      const int k1 = (t + 1) << 6;
      const int nxtA = (cur ^ 1) * 8192, nxtB = (cur ^ 1) * 4096;
#pragma unroll
      for (int i = 0; i < 4; ++i) async16(&As[nxtA + aDst[i]], aSrc[i] + k1);
#pragma unroll
      for (int i = 0; i < 2; ++i) {
        async16(&B1s[nxtB + bDst[i]], b1Src[i] + k1);
        async16(&B3s[nxtB + bDst[i]], b3Src[i] + k1);
      }
      asm volatile("s_waitcnt vmcnt(8)" ::: "memory");
    } else {
      asm volatile("s_waitcnt vmcnt(0)" ::: "memory");
    }
    SBAR();
    const int cA = cur * 8192, cB = cur * 4096;
#pragma unroll
    for (int s = 0; s < 2; ++s) {
      s16x8 a[4], b1f[2], b3f[2];
#pragma unroll
      for (int m = 0; m < 4; ++m) a[m] = *(const s16x8*)&As[cA + aOff[m][s]];
#pragma unroll
      for (int n = 0; n < 2; ++n) {
        b1f[n] = *(const s16x8*)&B1s[cB + bOff[n][s]];
        b3f[n] = *(const s16x8*)&B3s[cB + bOff[n][s]];
      }
#pragma unroll
      for (int m = 0; m < 4; ++m)
#pragma unroll
        for (int n = 0; n < 2; ++n) {
          acc1[m][n] = __builtin_amdgcn_mfma_f32_16x16x32_bf16(a[m], b1f[n], acc1[m][n], 0, 0, 0);
          acc3[m][n] = __builtin_amdgcn_mfma_f32_16x16x32_bf16(a[m], b3f[n], acc3[m][n], 0, 0, 0);
        }
    }
    if (more) { SBAR(); cur ^= 1; }
  }

  unsigned short* Grow = G + (size_t)rowbase * N;
#pragma unroll
  for (int m = 0; m < 4; ++m)
#pragma unroll
    for (int n = 0; n < 2; ++n)
#pragma unroll
      for (int q = 0; q < 4; ++q) {
        int r = wr * 64 + m * 16 + lhi * 4 + q;
        if (!ROUTED || (m0 + r) < cntE) {
          float h1 = acc1[m][n][q], h3 = acc3[m][n][q];
          float val = (h1 / (1.f + __expf(-h1))) * h3;
          Grow[(size_t)(m0 + r) * N + n0 + wc * 32 + n * 16 + llo] = f2bf(val);
        }
      }
}

// ---------------- GEMM2: out = A@W2^T (fp32, scattered when ROUTED) -----------
// Tile 64M x 128N, BK=64, 4 waves (2Mx2N, per-wave 32x64). LDS 48KB dbuf.
template <bool ROUTED>
__global__ __launch_bounds__(256, 3) void gemm2_kernel(
    const unsigned short* __restrict__ A0, const unsigned short* __restrict__ W2,
    float* __restrict__ Out, const int* __restrict__ cnt, const int* __restrict__ base,
    const int* __restrict__ dst, int K, int mtPerE) {
  int e, mt, cntE, rowbase;
  if constexpr (ROUTED) {
    e = blockIdx.x / mtPerE; mt = blockIdx.x % mtPerE;
    cntE = cnt[e];
    if (mt * 64 >= cntE) return;
    rowbase = base[e];
  } else {
    e = 0; mt = blockIdx.x; cntE = T_TOK; rowbase = 0;
  }
  const int m0 = mt * 64;
  const int n0 = blockIdx.y * 128;
  const unsigned short* A = A0 + (size_t)rowbase * K;
  const unsigned short* B = W2 + (size_t)e * DIMSZ * K + (size_t)n0 * K;

  __shared__ __align__(16) unsigned short As[2 * 64 * 64];
  __shared__ __align__(16) unsigned short Bs[2 * 128 * 64];

  const int tid = threadIdx.x;
  const int w = tid >> 6, lane = tid & 63;
  const int wr = w >> 1, wc = w & 1;
  const int lhi = lane >> 4, llo = lane & 15;

  const unsigned short* aSrc[2];
  int aDst[2];
#pragma unroll
  for (int i = 0; i < 2; ++i) {
    int L = i * 256 + tid, row = L >> 3, c = L & 7, sc = c ^ (row & 7);
    int ar = ROUTED ? min(m0 + row, cntE - 1) : (m0 + row);
    aSrc[i] = A + (size_t)ar * K + sc * 8;
    aDst[i] = (i * 256 + (tid & ~63)) * 8;
  }
  const unsigned short* bSrc[4];
  int bDst[4];
#pragma unroll
  for (int i = 0; i < 4; ++i) {
    int L = i * 256 + tid, row = L >> 3, c = L & 7, sc = c ^ (row & 7);
    bSrc[i] = B + (size_t)row * K + sc * 8;
    bDst[i] = (i * 256 + (tid & ~63)) * 8;
  }

  int aOff[2][2], bOff[4][2];
#pragma unroll
  for (int m = 0; m < 2; ++m) {
    int r = wr * 32 + m * 16 + llo;
#pragma unroll
    for (int s = 0; s < 2; ++s)
      aOff[m][s] = r * 64 + (((lhi + 4 * s) ^ (r & 7)) * 8);
  }
#pragma unroll
  for (int n = 0; n < 4; ++n) {
    int r = wc * 64 + n * 16 + llo;
#pragma unroll
    for (int s = 0; s < 2; ++s)
      bOff[n][s] = r * 64 + (((lhi + 4 * s) ^ (r & 7)) * 8);
  }

  f32x4 acc[2][4];
#pragma unroll
  for (int i = 0; i < 2; ++i)
#pragma unroll
    for (int j = 0; j < 4; ++j) acc[i][j] = f32x4{0.f, 0.f, 0.f, 0.f};

  const int nt = K >> 6;
  int cur = 0;
#pragma unroll
  for (int i = 0; i < 2; ++i) async16(&As[aDst[i]], aSrc[i]);
#pragma unroll
  for (int i = 0; i < 4; ++i) async16(&Bs[bDst[i]], bSrc[i]);

  for (int t = 0; t < nt; ++t) {
    const bool more = (t + 1) < nt;
    if (more) {
      const int k1 = (t + 1) << 6;
      const int nxtA = (cur ^ 1) * 4096, nxtB = (cur ^ 1) * 8192;
#pragma unroll
      for (int i = 0; i < 2; ++i) async16(&As[nxtA + aDst[i]], aSrc[i] + k1);
#pragma unroll
      for (int i = 0; i < 4; ++i) async16(&Bs[nxtB + bDst[i]], bSrc[i] + k1);
      asm volatile("s_waitcnt vmcnt(6)" ::: "memory");
    } else {
      asm volatile("s_waitcnt vmcnt(0)" ::: "memory");
    }
    SBAR();
    const int cA = cur * 4096, cB = cur * 8192;
#pragma unroll
    for (int s = 0; s < 2; ++s) {
      s16x8 a[2], b[4];
#pragma unroll
      for (int m = 0; m < 2; ++m) a[m] = *(const s16x8*)&As[cA + aOff[m][s]];
#pragma unroll
      for (int n = 0; n < 4; ++n) b[n] = *(const s16x8*)&Bs[cB + bOff[n][s]];
#pragma unroll
      for (int i = 0; i < 2; ++i)
#pragma unroll
        for (int j = 0; j < 4; ++j)
          acc[i][j] = __builtin_amdgcn_mfma_f32_16x16x32_bf16(a[i], b[j], acc[i][j], 0, 0, 0);
    }
    if (more) { SBAR(); cur ^= 1; }
  }

#pragma unroll
  for (int i = 0; i < 2; ++i)
#pragma unroll
    for (int j = 0; j < 4; ++j)
#pragma unroll
      for (int q = 0; q < 4; ++q) {
        int r = wr * 32 + i * 16 + lhi * 4 + q;
        if (!ROUTED || (m0 + r) < cntE) {
          int orow;
          if constexpr (ROUTED) orow = dst[rowbase + m0 + r];
          else                  orow = m0 + r;
          Out[(size_t)orow * DIMSZ + n0 + wc * 64 + j * 16 + llo] = acc[i][j][q];
        }
      }
}

// ---------------- final combine: out = shared + w0*p0 + w1*p1 ----------------
__global__ void combine_kernel(const float* __restrict__ shbuf, const float* __restrict__ pair,
                               const float* __restrict__ tw, float* __restrict__ out) {
  int i = blockIdx.x * blockDim.x + threadIdx.x;
  int t = i >> 7, c = i & 127;
  float w0 = tw[2 * t], w1 = tw[2 * t + 1];
  float4 a = ((const float4*)shbuf)[i];
  float4 p0 = ((const float4*)pair)[(size_t)(2 * t) * 128 + c];
  float4 p1 = ((const float4*)pair)[(size_t)(2 * t + 1) * 128 + c];
  float4 o;
  o.x = a.x + w0 * p0.x + w1 * p1.x;
  o.y = a.y + w0 * p0.y + w1 * p1.y;
  o.z = a.z + w0 * p0.z + w1 * p1.z;
  o.w = a.w + w0 * p0.w + w1 * p1.w;
  ((float4*)out)[i] = o;
}

extern "C" void kernel_launch(void* const* d_in, const int* in_sizes, int n_in,
                              void* d_out, int out_size, void* d_ws, size_t ws_size,
                              hipStream_t stream) {
  const float* x   = (const float*)d_in[0];
  const float* gw  = (const float*)d_in[1];
  const float* w1  = (const float*)d_in[2];
  const float* w3  = (const float*)d_in[3];
  const float* w2  = (const float*)d_in[4];
  const float* sw1 = (const float*)d_in[5];
  const float* sw3 = (const float*)d_in[6];
  const float* sw2 = (const float*)d_in[7];
  float* out = (float*)d_out;

  char* p = (char*)d_ws;
  auto alloc = [&](size_t bytes) {
    char* r = p;
    p += (bytes + 255) & ~(size_t)255;
    return r;
  };
  unsigned short* xb   = (unsigned short*)alloc((size_t)T_TOK * DIMSZ * 2);
  unsigned short* xg   = (unsigned short*)alloc((size_t)2 * T_TOK * DIMSZ * 2);
  unsigned short* w1b  = (unsigned short*)alloc((size_t)NE * HIDSZ * DIMSZ * 2);
  unsigned short* w3b  = (unsigned short*)alloc((size_t)NE * HIDSZ * DIMSZ * 2);
  unsigned short* w2b  = (unsigned short*)alloc((size_t)NE * DIMSZ * HIDSZ * 2);
  unsigned short* sw1b = (unsigned short*)alloc((size_t)SHIDSZ * DIMSZ * 2);
  unsigned short* sw3b = (unsigned short*)alloc((size_t)SHIDSZ * DIMSZ * 2);
  unsigned short* sw2b = (unsigned short*)alloc((size_t)DIMSZ * SHIDSZ * 2);
  unsigned short* g    = (unsigned short*)alloc((size_t)T_TOK * SHIDSZ * 2);
  float* pairout = (float*)alloc((size_t)2 * T_TOK * DIMSZ * 4);
  float* shbuf   = (float*)alloc((size_t)T_TOK * DIMSZ * 4);
  float* tw = (float*)alloc((size_t)2 * T_TOK * 4);
  int* ti   = (int*)alloc((size_t)2 * T_TOK * 4);
  int* tok  = (int*)alloc((size_t)2 * T_TOK * 4);
  int* dst  = (int*)alloc((size_t)2 * T_TOK * 4);
  int* meta = (int*)alloc(256);
  int* cnt = meta, *cursor = meta + 8, *base = meta + 16;

  auto cvt = [&](const float* s, unsigned short* d, size_t n) {
    int n4 = (int)(n / 4);
    cvt_bf16<<<(n4 + 255) / 256, 256, 0, stream>>>(s, d, n4);
  };
  cvt(x, xb, (size_t)T_TOK * DIMSZ);
  cvt(w1, w1b, (size_t)NE * HIDSZ * DIMSZ);
  cvt(w3, w3b, (size_t)NE * HIDSZ * DIMSZ);
  cvt(w2, w2b, (size_t)NE * DIMSZ * HIDSZ);
  cvt(sw1, sw1b, (size_t)SHIDSZ * DIMSZ);
  cvt(sw3, sw3b, (size_t)SHIDSZ * DIMSZ);
  cvt(sw2, sw2b, (size_t)DIMSZ * SHIDSZ);

  hipMemsetAsync(meta, 0, 64, stream);
  gate_kernel<<<GATE_BLOCKS, 256, 0, stream>>>(x, gw, tw, ti, cnt);
  scan_kernel<<<1, 64, 0, stream>>>(cnt, base, cursor);
  scatter_kernel<<<T_TOK / 256, 256, 0, stream>>>(ti, cursor, tok, dst);
  gather_kernel<<<(2 * T_TOK * 64) / 256, 256, 0, stream>>>(xb, tok, xg);

  // shared expert (dense) — g as [8192, 3072]
  gemm1_kernel<false><<<dim3(T_TOK / 128, SHIDSZ / 64), 256, 0, stream>>>(
      xb, sw1b, sw3b, g, nullptr, nullptr, DIMSZ, SHIDSZ, T_TOK / 128);
  gemm2_kernel<false><<<dim3(T_TOK / 64, DIMSZ / 128), 256, 0, stream>>>(
      g, sw2b, shbuf, nullptr, nullptr, nullptr, SHIDSZ, T_TOK / 64);

  // routed experts — g reused as [16384, 1536]
  gemm1_kernel<true><<<dim3(NE * (T_TOK / 128), HIDSZ / 64), 256, 0, stream>>>(
      xg, w1b, w3b, g, cnt, base, DIMSZ, HIDSZ, T_TOK / 128);
  gemm2_kernel<true><<<dim3(NE * (T_TOK / 64), DIMSZ / 128), 256, 0, stream>>>(
      g, w2b, pairout, cnt, base, dst, HIDSZ, T_TOK / 64);

  combine_kernel<<<(T_TOK * 128) / 256, 256, 0, stream>>>(shbuf, pairout, tw, out);
}

// Round 6
// 480.278 us; speedup vs baseline: 1.0426x; 1.0426x over previous
//
#include <hip/hip_runtime.h>

#define T_TOK 8192
#define DIMSZ 512
#define HIDSZ 1536
#define SHIDSZ 3072
#define NE 8

typedef __attribute__((ext_vector_type(4))) float f32x4;
typedef __attribute__((ext_vector_type(8))) short s16x8;

#define SBAR() __builtin_amdgcn_s_barrier()

__device__ __forceinline__ unsigned short f2bf(float f) {
  unsigned int u = __float_as_uint(f);
  u += 0x7fff + ((u >> 16) & 1);
  return (unsigned short)(u >> 16);
}

__device__ __forceinline__ void async16(void* lds, const void* g) {
  __builtin_amdgcn_global_load_lds((const __attribute__((address_space(1))) void*)g,
                                   (__attribute__((address_space(3))) void*)lds,
                                   16, 0, 0);
}

// ---------------- convert fp32 -> bf16 (vectorized) ----------------
__global__ void cvt_bf16(const float* __restrict__ s, unsigned short* __restrict__ d, int n4) {
  int i = blockIdx.x * blockDim.x + threadIdx.x;
  if (i < n4) {
    float4 v = ((const float4*)s)[i];
    ushort4 o;
    o.x = f2bf(v.x); o.y = f2bf(v.y); o.z = f2bf(v.z); o.w = f2bf(v.w);
    ((ushort4*)d)[i] = o;
  }
}

// ---------------- gate: logits, softmax, top-2, block-aggregated counts ------
#define GATE_BLOCKS 256
#define GATE_TPB (T_TOK / GATE_BLOCKS)
#define GATE_TPW (GATE_TPB / 4)

__global__ __launch_bounds__(256) void gate_kernel(
    const float* __restrict__ x, const float* __restrict__ gw,
    float* __restrict__ tw, int* __restrict__ ti, int* __restrict__ cnt) {
  __shared__ int lcnt[NE];
  const int tid = threadIdx.x;
  if (tid < NE) lcnt[tid] = 0;
  __syncthreads();
  const int w = tid >> 6, l = tid & 63;

  float gv[NE][8];
  const float* gbase = gw + l * 8;
#pragma unroll
  for (int e = 0; e < NE; ++e)
#pragma unroll
    for (int j = 0; j < 8; ++j) gv[e][j] = gbase[e * DIMSZ + j];

  const int tok0 = blockIdx.x * GATE_TPB + w * GATE_TPW;
  for (int it = 0; it < GATE_TPW; ++it) {
    const int t = tok0 + it;
    const float* xr = x + (size_t)t * DIMSZ + l * 8;
    float xv[8];
#pragma unroll
    for (int j = 0; j < 8; ++j) xv[j] = xr[j];
    float p[NE];
#pragma unroll
    for (int e = 0; e < NE; ++e) {
      float s = 0.f;
#pragma unroll
      for (int j = 0; j < 8; ++j) s = fmaf(xv[j], gv[e][j], s);
      p[e] = s;
    }
#pragma unroll
    for (int e = 0; e < NE; ++e) {
      float v = p[e];
#pragma unroll
      for (int off = 32; off > 0; off >>= 1) v += __shfl_xor(v, off);
      p[e] = v;
    }
    float m = p[0];
#pragma unroll
    for (int e = 1; e < NE; ++e) m = fmaxf(m, p[e]);
    float ex[NE], s = 0.f;
#pragma unroll
    for (int e = 0; e < NE; ++e) { ex[e] = __expf(p[e] - m); s += ex[e]; }
    float inv = 1.f / s;
    int e0 = 0; float v0 = p[0];
#pragma unroll
    for (int e = 1; e < NE; ++e) if (p[e] > v0) { v0 = p[e]; e0 = e; }
    int e1 = -1; float v1 = -3.4e38f;
#pragma unroll
    for (int e = 0; e < NE; ++e) if (e != e0 && p[e] > v1) { v1 = p[e]; e1 = e; }
    if (l == 0) {
      ti[2 * t] = e0;     tw[2 * t] = ex[e0] * inv;
      ti[2 * t + 1] = e1; tw[2 * t + 1] = ex[e1] * inv;
      atomicAdd(&lcnt[e0], 1);
      atomicAdd(&lcnt[e1], 1);
    }
  }
  __syncthreads();
  if (tid < NE) atomicAdd(&cnt[tid], lcnt[tid]);
}

// ---------------- exclusive scan over 8 expert counts ----------------
__global__ void scan_kernel(const int* __restrict__ cnt, int* __restrict__ base,
                            int* __restrict__ cursor) {
  if (threadIdx.x == 0 && blockIdx.x == 0) {
    int r = 0;
    for (int e = 0; e < NE; ++e) { base[e] = r; cursor[e] = r; r += cnt[e]; }
  }
}

// ---------------- scatter (block-aggregated) ----------------
__global__ __launch_bounds__(256) void scatter_kernel(
    const int* __restrict__ ti, int* __restrict__ cursor,
    int* __restrict__ tok, int* __restrict__ dst) {
  __shared__ int lcnt[NE], gbase[NE];
  const int tid = threadIdx.x;
  if (tid < NE) lcnt[tid] = 0;
  __syncthreads();
  const int t = blockIdx.x * 256 + tid;
  const int e0 = ti[2 * t], e1 = ti[2 * t + 1];
  const int p0 = atomicAdd(&lcnt[e0], 1);
  const int p1 = atomicAdd(&lcnt[e1], 1);
  __syncthreads();
  if (tid < NE) gbase[tid] = atomicAdd(&cursor[tid], lcnt[tid]);
  __syncthreads();
  const int i0 = gbase[e0] + p0, i1 = gbase[e1] + p1;
  tok[i0] = t; dst[i0] = 2 * t;
  tok[i1] = t; dst[i1] = 2 * t + 1;
}

// ---------------- gather bf16 x rows into bucket order ----------------
__global__ void gather_kernel(const unsigned short* __restrict__ xb,
                              const int* __restrict__ tok,
                              unsigned short* __restrict__ xg) {
  int i = blockIdx.x * blockDim.x + threadIdx.x;
  int entry = i >> 6, l = i & 63;
  int t = tok[entry];
  ((uint4*)xg)[entry * 64 + l] = ((const uint4*)xb)[t * 64 + l];
}

// =====================================================================
// 2-phase double-buffered pipeline (proven on gemm2 in R5) at
// OCCUPANCY-NEUTRAL LDS. Counted vmcnt mid-loop (never 0), raw s_barrier.
//   iter t: [stage t+1 -> buf^1] [vmcnt(N)] [SBAR] [compute buf] [SBAR]
// gemm1: BK=32 rows (64B = 4 chunks); swizzle involution
//   swz(r) = (r&3) ^ ((r>>2)&3)   (chunk XOR; 2-way residual = free)
// gemm2: BK=64 rows (128B = 8 chunks); swz(r) = r&7.
// Rule 21: LDS dest linear, global source pre-swizzled, read same XOR.
// =====================================================================

// ---------------- GEMM1: g = silu(A@W1^T) * (A@W3^T), bf16 out ----------------
// Tile 128M x 64N, BK=32, dbuf LDS 32KB total, 4 waves (2Mx2N, 64x32 dual).
template <bool ROUTED>
__global__ __launch_bounds__(256, 3) void gemm1_kernel(
    const unsigned short* __restrict__ A0, const unsigned short* __restrict__ W1,
    const unsigned short* __restrict__ W3, unsigned short* __restrict__ G,
    const int* __restrict__ cnt, const int* __restrict__ base,
    int K, int N, int mtPerE) {
  int e, mt, cntE, rowbase;
  if constexpr (ROUTED) {
    e = blockIdx.x / mtPerE; mt = blockIdx.x % mtPerE;
    cntE = cnt[e];
    if (mt * 128 >= cntE) return;
    rowbase = base[e];
  } else {
    e = 0; mt = blockIdx.x; cntE = T_TOK; rowbase = 0;
  }
  const int m0 = mt * 128;
  const int n0 = blockIdx.y * 64;
  const unsigned short* A = A0 + (size_t)rowbase * K;
  const unsigned short* B1 = W1 + (size_t)e * N * K + (size_t)n0 * K;
  const unsigned short* B3 = W3 + (size_t)e * N * K + (size_t)n0 * K;

  __shared__ __align__(16) unsigned short As[2 * 128 * 32];  // 16KB
  __shared__ __align__(16) unsigned short B1s[2 * 64 * 32];  //  8KB
  __shared__ __align__(16) unsigned short B3s[2 * 64 * 32];  //  8KB

  const int tid = threadIdx.x;
  const int w = tid >> 6, lane = tid & 63;
  const int wr = w >> 1, wc = w & 1;
  const int lhi = lane >> 4, llo = lane & 15;

  // staging: pre-swizzled global sources, linear LDS dests (wave-uniform base)
  const unsigned short* aSrc[2];
  int aDst[2];
#pragma unroll
  for (int i = 0; i < 2; ++i) {
    int L = i * 256 + tid, row = L >> 2, c = L & 3;
    int sc = c ^ (row & 3) ^ ((row >> 2) & 3);
    int ar = ROUTED ? min(m0 + row, cntE - 1) : (m0 + row);
    aSrc[i] = A + (size_t)ar * K + sc * 8;
    aDst[i] = (i * 256 + (tid & ~63)) * 8;
  }
  const unsigned short *b1Src, *b3Src;
  int bDst;
  {
    int L = tid, row = L >> 2, c = L & 3;
    int sc = c ^ (row & 3) ^ ((row >> 2) & 3);
    b1Src = B1 + (size_t)row * K + sc * 8;
    b3Src = B3 + (size_t)row * K + sc * 8;
    bDst = (tid & ~63) * 8;
  }

  // swizzled ds_read offsets (ushort units within one buffer)
  int aOff[4], bOff[2];
#pragma unroll
  for (int m = 0; m < 4; ++m) {
    int r = wr * 64 + m * 16 + llo;
    aOff[m] = r * 32 + ((lhi ^ (r & 3) ^ ((r >> 2) & 3)) * 8);
  }
#pragma unroll
  for (int n = 0; n < 2; ++n) {
    int r = wc * 32 + n * 16 + llo;
    bOff[n] = r * 32 + ((lhi ^ (r & 3) ^ ((r >> 2) & 3)) * 8);
  }

  f32x4 acc1[4][2], acc3[4][2];
#pragma unroll
  for (int m = 0; m < 4; ++m)
#pragma unroll
    for (int n = 0; n < 2; ++n) {
      acc1[m][n] = f32x4{0.f, 0.f, 0.f, 0.f};
      acc3[m][n] = f32x4{0.f, 0.f, 0.f, 0.f};
    }

  const int nt = K >> 5;  // 16
  int cur = 0;
  // prologue: stage tile 0 into buf 0 (4 loads)
  async16(&As[aDst[0]], aSrc[0]);
  async16(&As[aDst[1]], aSrc[1]);
  async16(&B1s[bDst], b1Src);
  async16(&B3s[bDst], b3Src);

  for (int t = 0; t < nt; ++t) {
    const bool more = (t + 1) < nt;
    if (more) {
      const int k1 = (t + 1) << 5;
      const int nxtA = (cur ^ 1) * 4096, nxtB = (cur ^ 1) * 2048;
      async16(&As[nxtA + aDst[0]], aSrc[0] + k1);
      async16(&As[nxtA + aDst[1]], aSrc[1] + k1);
      async16(&B1s[nxtB + bDst], b1Src + k1);
      async16(&B3s[nxtB + bDst], b3Src + k1);
      asm volatile("s_waitcnt vmcnt(4)" ::: "memory");
    } else {
      asm volatile("s_waitcnt vmcnt(0)" ::: "memory");
    }
    SBAR();
    const int cA = cur * 4096, cB = cur * 2048;
    s16x8 a[4], b1f[2], b3f[2];
#pragma unroll
    for (int m = 0; m < 4; ++m) a[m] = *(const s16x8*)&As[cA + aOff[m]];
#pragma unroll
    for (int n = 0; n < 2; ++n) {
      b1f[n] = *(const s16x8*)&B1s[cB + bOff[n]];
      b3f[n] = *(const s16x8*)&B3s[cB + bOff[n]];
    }
#pragma unroll
    for (int m = 0; m < 4; ++m)
#pragma unroll
      for (int n = 0; n < 2; ++n) {
        acc1[m][n] = __builtin_amdgcn_mfma_f32_16x16x32_bf16(a[m], b1f[n], acc1[m][n], 0, 0, 0);
        acc3[m][n] = __builtin_amdgcn_mfma_f32_16x16x32_bf16(a[m], b3f[n], acc3[m][n], 0, 0, 0);
      }
    if (more) { SBAR(); cur ^= 1; }
  }

  unsigned short* Grow = G + (size_t)rowbase * N;
#pragma unroll
  for (int m = 0; m < 4; ++m)
#pragma unroll
    for (int n = 0; n < 2; ++n)
#pragma unroll
      for (int q = 0; q < 4; ++q) {
        int r = wr * 64 + m * 16 + lhi * 4 + q;
        if (!ROUTED || (m0 + r) < cntE) {
          float h1 = acc1[m][n][q], h3 = acc3[m][n][q];
          float val = (h1 / (1.f + __expf(-h1))) * h3;
          Grow[(size_t)(m0 + r) * N + n0 + wc * 32 + n * 16 + llo] = f2bf(val);
        }
      }
}

// ---------------- GEMM2: out = A@W2^T (fp32, scattered when ROUTED) -----------
// Tile 64M x 128N, BK=64, 4 waves (2Mx2N, per-wave 32x64). LDS 48KB dbuf.
// (unchanged from R5 — measured ~70 µs by subtraction)
template <bool ROUTED>
__global__ __launch_bounds__(256, 3) void gemm2_kernel(
    const unsigned short* __restrict__ A0, const unsigned short* __restrict__ W2,
    float* __restrict__ Out, const int* __restrict__ cnt, const int* __restrict__ base,
    const int* __restrict__ dst, int K, int mtPerE) {
  int e, mt, cntE, rowbase;
  if constexpr (ROUTED) {
    e = blockIdx.x / mtPerE; mt = blockIdx.x % mtPerE;
    cntE = cnt[e];
    if (mt * 64 >= cntE) return;
    rowbase = base[e];
  } else {
    e = 0; mt = blockIdx.x; cntE = T_TOK; rowbase = 0;
  }
  const int m0 = mt * 64;
  const int n0 = blockIdx.y * 128;
  const unsigned short* A = A0 + (size_t)rowbase * K;
  const unsigned short* B = W2 + (size_t)e * DIMSZ * K + (size_t)n0 * K;

  __shared__ __align__(16) unsigned short As[2 * 64 * 64];
  __shared__ __align__(16) unsigned short Bs[2 * 128 * 64];

  const int tid = threadIdx.x;
  const int w = tid >> 6, lane = tid & 63;
  const int wr = w >> 1, wc = w & 1;
  const int lhi = lane >> 4, llo = lane & 15;

  const unsigned short* aSrc[2];
  int aDst[2];
#pragma unroll
  for (int i = 0; i < 2; ++i) {
    int L = i * 256 + tid, row = L >> 3, c = L & 7, sc = c ^ (row & 7);
    int ar = ROUTED ? min(m0 + row, cntE - 1) : (m0 + row);
    aSrc[i] = A + (size_t)ar * K + sc * 8;
    aDst[i] = (i * 256 + (tid & ~63)) * 8;
  }
  const unsigned short* bSrc[4];
  int bDst[4];
#pragma unroll
  for (int i = 0; i < 4; ++i) {
    int L = i * 256 + tid, row = L >> 3, c = L & 7, sc = c ^ (row & 7);
    bSrc[i] = B + (size_t)row * K + sc * 8;
    bDst[i] = (i * 256 + (tid & ~63)) * 8;
  }

  int aOff[2][2], bOff[4][2];
#pragma unroll
  for (int m = 0; m < 2; ++m) {
    int r = wr * 32 + m * 16 + llo;
#pragma unroll
    for (int s = 0; s < 2; ++s)
      aOff[m][s] = r * 64 + (((lhi + 4 * s) ^ (r & 7)) * 8);
  }
#pragma unroll
  for (int n = 0; n < 4; ++n) {
    int r = wc * 64 + n * 16 + llo;
#pragma unroll
    for (int s = 0; s < 2; ++s)
      bOff[n][s] = r * 64 + (((lhi + 4 * s) ^ (r & 7)) * 8);
  }

  f32x4 acc[2][4];
#pragma unroll
  for (int i = 0; i < 2; ++i)
#pragma unroll
    for (int j = 0; j < 4; ++j) acc[i][j] = f32x4{0.f, 0.f, 0.f, 0.f};

  const int nt = K >> 6;
  int cur = 0;
#pragma unroll
  for (int i = 0; i < 2; ++i) async16(&As[aDst[i]], aSrc[i]);
#pragma unroll
  for (int i = 0; i < 4; ++i) async16(&Bs[bDst[i]], bSrc[i]);

  for (int t = 0; t < nt; ++t) {
    const bool more = (t + 1) < nt;
    if (more) {
      const int k1 = (t + 1) << 6;
      const int nxtA = (cur ^ 1) * 4096, nxtB = (cur ^ 1) * 8192;
#pragma unroll
      for (int i = 0; i < 2; ++i) async16(&As[nxtA + aDst[i]], aSrc[i] + k1);
#pragma unroll
      for (int i = 0; i < 4; ++i) async16(&Bs[nxtB + bDst[i]], bSrc[i] + k1);
      asm volatile("s_waitcnt vmcnt(6)" ::: "memory");
    } else {
      asm volatile("s_waitcnt vmcnt(0)" ::: "memory");
    }
    SBAR();
    const int cA = cur * 4096, cB = cur * 8192;
#pragma unroll
    for (int s = 0; s < 2; ++s) {
      s16x8 a[2], b[4];
#pragma unroll
      for (int m = 0; m < 2; ++m) a[m] = *(const s16x8*)&As[cA + aOff[m][s]];
#pragma unroll
      for (int n = 0; n < 4; ++n) b[n] = *(const s16x8*)&Bs[cB + bOff[n][s]];
#pragma unroll
      for (int i = 0; i < 2; ++i)
#pragma unroll
        for (int j = 0; j < 4; ++j)
          acc[i][j] = __builtin_amdgcn_mfma_f32_16x16x32_bf16(a[i], b[j], acc[i][j], 0, 0, 0);
    }
    if (more) { SBAR(); cur ^= 1; }
  }

#pragma unroll
  for (int i = 0; i < 2; ++i)
#pragma unroll
    for (int j = 0; j < 4; ++j)
#pragma unroll
      for (int q = 0; q < 4; ++q) {
        int r = wr * 32 + i * 16 + lhi * 4 + q;
        if (!ROUTED || (m0 + r) < cntE) {
          int orow;
          if constexpr (ROUTED) orow = dst[rowbase + m0 + r];
          else                  orow = m0 + r;
          Out[(size_t)orow * DIMSZ + n0 + wc * 64 + j * 16 + llo] = acc[i][j][q];
        }
      }
}

// ---------------- final combine: out = shared + w0*p0 + w1*p1 ----------------
__global__ void combine_kernel(const float* __restrict__ shbuf, const float* __restrict__ pair,
                               const float* __restrict__ tw, float* __restrict__ out) {
  int i = blockIdx.x * blockDim.x + threadIdx.x;
  int t = i >> 7, c = i & 127;
  float w0 = tw[2 * t], w1 = tw[2 * t + 1];
  float4 a = ((const float4*)shbuf)[i];
  float4 p0 = ((const float4*)pair)[(size_t)(2 * t) * 128 + c];
  float4 p1 = ((const float4*)pair)[(size_t)(2 * t + 1) * 128 + c];
  float4 o;
  o.x = a.x + w0 * p0.x + w1 * p1.x;
  o.y = a.y + w0 * p0.y + w1 * p1.y;
  o.z = a.z + w0 * p0.z + w1 * p1.z;
  o.w = a.w + w0 * p0.w + w1 * p1.w;
  ((float4*)out)[i] = o;
}

extern "C" void kernel_launch(void* const* d_in, const int* in_sizes, int n_in,
                              void* d_out, int out_size, void* d_ws, size_t ws_size,
                              hipStream_t stream) {
  const float* x   = (const float*)d_in[0];
  const float* gw  = (const float*)d_in[1];
  const float* w1  = (const float*)d_in[2];
  const float* w3  = (const float*)d_in[3];
  const float* w2  = (const float*)d_in[4];
  const float* sw1 = (const float*)d_in[5];
  const float* sw3 = (const float*)d_in[6];
  const float* sw2 = (const float*)d_in[7];
  float* out = (float*)d_out;

  char* p = (char*)d_ws;
  auto alloc = [&](size_t bytes) {
    char* r = p;
    p += (bytes + 255) & ~(size_t)255;
    return r;
  };
  unsigned short* xb   = (unsigned short*)alloc((size_t)T_TOK * DIMSZ * 2);
  unsigned short* xg   = (unsigned short*)alloc((size_t)2 * T_TOK * DIMSZ * 2);
  unsigned short* w1b  = (unsigned short*)alloc((size_t)NE * HIDSZ * DIMSZ * 2);
  unsigned short* w3b  = (unsigned short*)alloc((size_t)NE * HIDSZ * DIMSZ * 2);
  unsigned short* w2b  = (unsigned short*)alloc((size_t)NE * DIMSZ * HIDSZ * 2);
  unsigned short* sw1b = (unsigned short*)alloc((size_t)SHIDSZ * DIMSZ * 2);
  unsigned short* sw3b = (unsigned short*)alloc((size_t)SHIDSZ * DIMSZ * 2);
  unsigned short* sw2b = (unsigned short*)alloc((size_t)DIMSZ * SHIDSZ * 2);
  unsigned short* g    = (unsigned short*)alloc((size_t)T_TOK * SHIDSZ * 2);
  float* pairout = (float*)alloc((size_t)2 * T_TOK * DIMSZ * 4);
  float* shbuf   = (float*)alloc((size_t)T_TOK * DIMSZ * 4);
  float* tw = (float*)alloc((size_t)2 * T_TOK * 4);
  int* ti   = (int*)alloc((size_t)2 * T_TOK * 4);
  int* tok  = (int*)alloc((size_t)2 * T_TOK * 4);
  int* dst  = (int*)alloc((size_t)2 * T_TOK * 4);
  int* meta = (int*)alloc(256);
  int* cnt = meta, *cursor = meta + 8, *base = meta + 16;

  auto cvt = [&](const float* s, unsigned short* d, size_t n) {
    int n4 = (int)(n / 4);
    cvt_bf16<<<(n4 + 255) / 256, 256, 0, stream>>>(s, d, n4);
  };
  cvt(x, xb, (size_t)T_TOK * DIMSZ);
  cvt(w1, w1b, (size_t)NE * HIDSZ * DIMSZ);
  cvt(w3, w3b, (size_t)NE * HIDSZ * DIMSZ);
  cvt(w2, w2b, (size_t)NE * DIMSZ * HIDSZ);
  cvt(sw1, sw1b, (size_t)SHIDSZ * DIMSZ);
  cvt(sw3, sw3b, (size_t)SHIDSZ * DIMSZ);
  cvt(sw2, sw2b, (size_t)DIMSZ * SHIDSZ);

  hipMemsetAsync(meta, 0, 64, stream);
  gate_kernel<<<GATE_BLOCKS, 256, 0, stream>>>(x, gw, tw, ti, cnt);
  scan_kernel<<<1, 64, 0, stream>>>(cnt, base, cursor);
  scatter_kernel<<<T_TOK / 256, 256, 0, stream>>>(ti, cursor, tok, dst);
  gather_kernel<<<(2 * T_TOK * 64) / 256, 256, 0, stream>>>(xb, tok, xg);

  // shared expert (dense) — g as [8192, 3072]
  gemm1_kernel<false><<<dim3(T_TOK / 128, SHIDSZ / 64), 256, 0, stream>>>(
      xb, sw1b, sw3b, g, nullptr, nullptr, DIMSZ, SHIDSZ, T_TOK / 128);
  gemm2_kernel<false><<<dim3(T_TOK / 64, DIMSZ / 128), 256, 0, stream>>>(
      g, sw2b, shbuf, nullptr, nullptr, nullptr, SHIDSZ, T_TOK / 64);

  // routed experts — g reused as [16384, 1536]
  gemm1_kernel<true><<<dim3(NE * (T_TOK / 128), HIDSZ / 64), 256, 0, stream>>>(
      xg, w1b, w3b, g, cnt, base, DIMSZ, HIDSZ, T_TOK / 128);
  gemm2_kernel<true><<<dim3(NE * (T_TOK / 64), DIMSZ / 128), 256, 0, stream>>>(
      g, w2b, pairout, cnt, base, dst, HIDSZ, T_TOK / 64);

  combine_kernel<<<(T_TOK * 128) / 256, 256, 0, stream>>>(shbuf, pairout, tw, out);
}

// Round 11
// 429.903 us; speedup vs baseline: 1.1647x; 1.1172x over previous
//
#include <hip/hip_runtime.h>

#define T_TOK 8192
#define DIMSZ 512
#define HIDSZ 1536
#define SHIDSZ 3072
#define NE 8

typedef __attribute__((ext_vector_type(4))) float f32x4;
typedef __attribute__((ext_vector_type(8))) short s16x8;

__device__ __forceinline__ unsigned short f2bf(float f) {
  unsigned int u = __float_as_uint(f);
  u += 0x7fff + ((u >> 16) & 1);
  return (unsigned short)(u >> 16);
}

__device__ __forceinline__ void async16(void* lds, const void* g) {
  __builtin_amdgcn_global_load_lds((const __attribute__((address_space(1))) void*)g,
                                   (__attribute__((address_space(3))) void*)lds,
                                   16, 0, 0);
}

// ---------------- convert fp32 -> bf16 (vectorized) ----------------
__global__ void cvt_bf16(const float* __restrict__ s, unsigned short* __restrict__ d, int n4) {
  int i = blockIdx.x * blockDim.x + threadIdx.x;
  if (i < n4) {
    float4 v = ((const float4*)s)[i];
    ushort4 o;
    o.x = f2bf(v.x); o.y = f2bf(v.y); o.z = f2bf(v.z); o.w = f2bf(v.w);
    ((ushort4*)d)[i] = o;
  }
}

// ---------------- gate: logits, softmax, top-2, block-aggregated counts ------
#define GATE_BLOCKS 256
#define GATE_TPB (T_TOK / GATE_BLOCKS)
#define GATE_TPW (GATE_TPB / 4)

__global__ __launch_bounds__(256) void gate_kernel(
    const float* __restrict__ x, const float* __restrict__ gw,
    float* __restrict__ tw, int* __restrict__ ti, int* __restrict__ cnt) {
  __shared__ int lcnt[NE];
  const int tid = threadIdx.x;
  if (tid < NE) lcnt[tid] = 0;
  __syncthreads();
  const int w = tid >> 6, l = tid & 63;

  float gv[NE][8];
  const float* gbase = gw + l * 8;
#pragma unroll
  for (int e = 0; e < NE; ++e)
#pragma unroll
    for (int j = 0; j < 8; ++j) gv[e][j] = gbase[e * DIMSZ + j];

  const int tok0 = blockIdx.x * GATE_TPB + w * GATE_TPW;
  for (int it = 0; it < GATE_TPW; ++it) {
    const int t = tok0 + it;
    const float* xr = x + (size_t)t * DIMSZ + l * 8;
    float xv[8];
#pragma unroll
    for (int j = 0; j < 8; ++j) xv[j] = xr[j];
    float p[NE];
#pragma unroll
    for (int e = 0; e < NE; ++e) {
      float s = 0.f;
#pragma unroll
      for (int j = 0; j < 8; ++j) s = fmaf(xv[j], gv[e][j], s);
      p[e] = s;
    }
#pragma unroll
    for (int e = 0; e < NE; ++e) {
      float v = p[e];
#pragma unroll
      for (int off = 32; off > 0; off >>= 1) v += __shfl_xor(v, off);
      p[e] = v;
    }
    float m = p[0];
#pragma unroll
    for (int e = 1; e < NE; ++e) m = fmaxf(m, p[e]);
    float ex[NE], s = 0.f;
#pragma unroll
    for (int e = 0; e < NE; ++e) { ex[e] = __expf(p[e] - m); s += ex[e]; }
    float inv = 1.f / s;
    int e0 = 0; float v0 = p[0];
#pragma unroll
    for (int e = 1; e < NE; ++e) if (p[e] > v0) { v0 = p[e]; e0 = e; }
    int e1 = -1; float v1 = -3.4e38f;
#pragma unroll
    for (int e = 0; e < NE; ++e) if (e != e0 && p[e] > v1) { v1 = p[e]; e1 = e; }
    if (l == 0) {
      ti[2 * t] = e0;     tw[2 * t] = ex[e0] * inv;
      ti[2 * t + 1] = e1; tw[2 * t + 1] = ex[e1] * inv;
      atomicAdd(&lcnt[e0], 1);
      atomicAdd(&lcnt[e1], 1);
    }
  }
  __syncthreads();
  if (tid < NE) atomicAdd(&cnt[tid], lcnt[tid]);
}

// ---------------- exclusive scan over 8 expert counts ----------------
__global__ void scan_kernel(const int* __restrict__ cnt, int* __restrict__ base,
                            int* __restrict__ cursor) {
  if (threadIdx.x == 0 && blockIdx.x == 0) {
    int r = 0;
    for (int e = 0; e < NE; ++e) { base[e] = r; cursor[e] = r; r += cnt[e]; }
  }
}

// ---------------- scatter (block-aggregated) ----------------
__global__ __launch_bounds__(256) void scatter_kernel(
    const int* __restrict__ ti, int* __restrict__ cursor,
    int* __restrict__ tok, int* __restrict__ dst) {
  __shared__ int lcnt[NE], gbase[NE];
  const int tid = threadIdx.x;
  if (tid < NE) lcnt[tid] = 0;
  __syncthreads();
  const int t = blockIdx.x * 256 + tid;
  const int e0 = ti[2 * t], e1 = ti[2 * t + 1];
  const int p0 = atomicAdd(&lcnt[e0], 1);
  const int p1 = atomicAdd(&lcnt[e1], 1);
  __syncthreads();
  if (tid < NE) gbase[tid] = atomicAdd(&cursor[tid], lcnt[tid]);
  __syncthreads();
  const int i0 = gbase[e0] + p0, i1 = gbase[e1] + p1;
  tok[i0] = t; dst[i0] = 2 * t;
  tok[i1] = t; dst[i1] = 2 * t + 1;
}

// =====================================================================
// GEMM1 (merged routed+shared): g = silu(A@W1^T) * (A@W3^T), bf16 out.
// R4-proven core: tile 128M x 64N, BK=64 (128B rows, swz chunk^(row&7),
// 0 conflicts), single-buffered LDS 32KB, __launch_bounds__(256,3).
// Expert e<8: routed (A rows gathered on the fly via tok[]); e==8: shared.
// =====================================================================
__global__ __launch_bounds__(256, 3) void gemm1_all(
    const unsigned short* __restrict__ xb, const int* __restrict__ tok,
    const unsigned short* __restrict__ w1b, const unsigned short* __restrict__ w3b,
    const unsigned short* __restrict__ sw1b, const unsigned short* __restrict__ sw3b,
    unsigned short* __restrict__ g_rt, unsigned short* __restrict__ g_sh,
    const int* __restrict__ cnt, const int* __restrict__ base) {
  const int bx = blockIdx.x;
  const int e = bx >> 6, mt = bx & 63;
  const int n0 = blockIdx.y * 64;
  int cntE, rowbase, N;
  const unsigned short *B1, *B3;
  unsigned short* G;
  bool indirect;
  if (e < NE) {
    N = HIDSZ;
    if (n0 >= HIDSZ) return;
    cntE = cnt[e];
    if (mt * 128 >= cntE) return;
    rowbase = base[e];
    B1 = w1b + (size_t)e * HIDSZ * DIMSZ + (size_t)n0 * DIMSZ;
    B3 = w3b + (size_t)e * HIDSZ * DIMSZ + (size_t)n0 * DIMSZ;
    G = g_rt + (size_t)rowbase * HIDSZ;
    indirect = true;
  } else {
    N = SHIDSZ; cntE = T_TOK; rowbase = 0;
    B1 = sw1b + (size_t)n0 * DIMSZ;
    B3 = sw3b + (size_t)n0 * DIMSZ;
    G = g_sh;
    indirect = false;
  }
  const int m0 = mt * 128;

  __shared__ __align__(16) unsigned short As[128 * 64];
  __shared__ __align__(16) unsigned short B1s[64 * 64];
  __shared__ __align__(16) unsigned short B3s[64 * 64];

  const int tid = threadIdx.x;
  const int w = tid >> 6, lane = tid & 63;
  const int wr = w >> 1, wc = w & 1;
  const int lhi = lane >> 4, llo = lane & 15;

  // staging: pre-swizzled global chunk sources + linear LDS dests
  const unsigned short* aSrc[4];
  int aDst[4];
#pragma unroll
  for (int i = 0; i < 4; ++i) {
    int L = i * 256 + tid, row = L >> 3, c = L & 7, sc = c ^ (row & 7);
    int ar = min(m0 + row, cntE - 1);
    int rowg = indirect ? tok[rowbase + ar] : ar;
    aSrc[i] = xb + (size_t)rowg * DIMSZ + sc * 8;
    aDst[i] = (i * 256 + (tid & ~63)) * 8;
  }
  const unsigned short *b1Src[2], *b3Src[2];
  int bDst[2];
#pragma unroll
  for (int i = 0; i < 2; ++i) {
    int L = i * 256 + tid, row = L >> 3, c = L & 7, sc = c ^ (row & 7);
    b1Src[i] = B1 + (size_t)row * DIMSZ + sc * 8;
    b3Src[i] = B3 + (size_t)row * DIMSZ + sc * 8;
    bDst[i] = (i * 256 + (tid & ~63)) * 8;
  }

  // swizzled ds_read offsets (ushort units)
  int aOff[4][2], bOff[2][2];
#pragma unroll
  for (int m = 0; m < 4; ++m) {
    int r = wr * 64 + m * 16 + llo;
#pragma unroll
    for (int s = 0; s < 2; ++s)
      aOff[m][s] = r * 64 + (((lhi + 4 * s) ^ (r & 7)) * 8);
  }
#pragma unroll
  for (int n = 0; n < 2; ++n) {
    int r = wc * 32 + n * 16 + llo;
#pragma unroll
    for (int s = 0; s < 2; ++s)
      bOff[n][s] = r * 64 + (((lhi + 4 * s) ^ (r & 7)) * 8);
  }

  f32x4 acc1[4][2], acc3[4][2];
#pragma unroll
  for (int m = 0; m < 4; ++m)
#pragma unroll
    for (int n = 0; n < 2; ++n) {
      acc1[m][n] = f32x4{0.f, 0.f, 0.f, 0.f};
      acc3[m][n] = f32x4{0.f, 0.f, 0.f, 0.f};
    }

  for (int k0 = 0; k0 < DIMSZ; k0 += 64) {
#pragma unroll
    for (int i = 0; i < 4; ++i) async16(&As[aDst[i]], aSrc[i] + k0);
#pragma unroll
    for (int i = 0; i < 2; ++i) {
      async16(&B1s[bDst[i]], b1Src[i] + k0);
      async16(&B3s[bDst[i]], b3Src[i] + k0);
    }
    __syncthreads();
#pragma unroll
    for (int s = 0; s < 2; ++s) {
      s16x8 a[4], b1f[2], b3f[2];
#pragma unroll
      for (int m = 0; m < 4; ++m) a[m] = *(const s16x8*)&As[aOff[m][s]];
#pragma unroll
      for (int n = 0; n < 2; ++n) {
        b1f[n] = *(const s16x8*)&B1s[bOff[n][s]];
        b3f[n] = *(const s16x8*)&B3s[bOff[n][s]];
      }
#pragma unroll
      for (int m = 0; m < 4; ++m)
#pragma unroll
        for (int n = 0; n < 2; ++n) {
          acc1[m][n] = __builtin_amdgcn_mfma_f32_16x16x32_bf16(a[m], b1f[n], acc1[m][n], 0, 0, 0);
          acc3[m][n] = __builtin_amdgcn_mfma_f32_16x16x32_bf16(a[m], b3f[n], acc3[m][n], 0, 0, 0);
        }
    }
    __syncthreads();
  }

#pragma unroll
  for (int m = 0; m < 4; ++m)
#pragma unroll
    for (int n = 0; n < 2; ++n)
#pragma unroll
      for (int q = 0; q < 4; ++q) {
        int r = wr * 64 + m * 16 + lhi * 4 + q;
        if (m0 + r < cntE) {
          float h1 = acc1[m][n][q], h3 = acc3[m][n][q];
          float val = (h1 / (1.f + __expf(-h1))) * h3;
          G[(size_t)(m0 + r) * N + n0 + wc * 32 + n * 16 + llo] = f2bf(val);
        }
      }
}

// =====================================================================
// GEMM2 (merged routed+shared, combine fused): out += weight * (A@W2^T).
// R5-proven core: tile 64M x 128N, BK=64, dbuf 48KB, counted vmcnt(6),
// raw s_barrier, __launch_bounds__(256,3). Routed: weight=tw[dst], row=dst>>1,
// atomicAdd. Shared: weight=1. out must be pre-zeroed.
// =====================================================================
__global__ __launch_bounds__(256, 3) void gemm2_all(
    const unsigned short* __restrict__ g_rt, const unsigned short* __restrict__ g_sh,
    const unsigned short* __restrict__ w2b, const unsigned short* __restrict__ sw2b,
    const int* __restrict__ cnt, const int* __restrict__ base,
    const int* __restrict__ dst, const float* __restrict__ tw,
    float* __restrict__ out) {
  const int bx = blockIdx.x;
  const int e = bx >> 7, mt = bx & 127;
  const int n0 = blockIdx.y * 128;
  int cntE, rowbase, K;
  const unsigned short *A, *B;
  bool routed;
  if (e < NE) {
    cntE = cnt[e];
    if (mt * 64 >= cntE) return;
    rowbase = base[e];
    A = g_rt + (size_t)rowbase * HIDSZ;
    B = w2b + (size_t)e * DIMSZ * HIDSZ + (size_t)n0 * HIDSZ;
    K = HIDSZ;
    routed = true;
  } else {
    cntE = T_TOK; rowbase = 0;
    A = g_sh;
    B = sw2b + (size_t)n0 * SHIDSZ;
    K = SHIDSZ;
    routed = false;
  }
  const int m0 = mt * 64;

  __shared__ __align__(16) unsigned short As[2 * 64 * 64];
  __shared__ __align__(16) unsigned short Bs[2 * 128 * 64];

  const int tid = threadIdx.x;
  const int w = tid >> 6, lane = tid & 63;
  const int wr = w >> 1, wc = w & 1;
  const int lhi = lane >> 4, llo = lane & 15;

  const unsigned short* aSrc[2];
  int aDst[2];
#pragma unroll
  for (int i = 0; i < 2; ++i) {
    int L = i * 256 + tid, row = L >> 3, c = L & 7, sc = c ^ (row & 7);
    int ar = min(m0 + row, cntE - 1);
    aSrc[i] = A + (size_t)ar * K + sc * 8;
    aDst[i] = (i * 256 + (tid & ~63)) * 8;
  }
  const unsigned short* bSrc[4];
  int bDst[4];
#pragma unroll
  for (int i = 0; i < 4; ++i) {
    int L = i * 256 + tid, row = L >> 3, c = L & 7, sc = c ^ (row & 7);
    bSrc[i] = B + (size_t)row * K + sc * 8;
    bDst[i] = (i * 256 + (tid & ~63)) * 8;
  }

  int aOff[2][2], bOff[4][2];
#pragma unroll
  for (int m = 0; m < 2; ++m) {
    int r = wr * 32 + m * 16 + llo;
#pragma unroll
    for (int s = 0; s < 2; ++s)
      aOff[m][s] = r * 64 + (((lhi + 4 * s) ^ (r & 7)) * 8);
  }
#pragma unroll
  for (int n = 0; n < 4; ++n) {
    int r = wc * 64 + n * 16 + llo;
#pragma unroll
    for (int s = 0; s < 2; ++s)
      bOff[n][s] = r * 64 + (((lhi + 4 * s) ^ (r & 7)) * 8);
  }

  f32x4 acc[2][4];
#pragma unroll
  for (int i = 0; i < 2; ++i)
#pragma unroll
    for (int j = 0; j < 4; ++j) acc[i][j] = f32x4{0.f, 0.f, 0.f, 0.f};

  const int nt = K >> 6;
  int cur = 0;
#pragma unroll
  for (int i = 0; i < 2; ++i) async16(&As[aDst[i]], aSrc[i]);
#pragma unroll
  for (int i = 0; i < 4; ++i) async16(&Bs[bDst[i]], bSrc[i]);

  for (int t = 0; t < nt; ++t) {
    const bool more = (t + 1) < nt;
    if (more) {
      const int k1 = (t + 1) << 6;
      const int nxtA = (cur ^ 1) * 4096, nxtB = (cur ^ 1) * 8192;
#pragma unroll
      for (int i = 0; i < 2; ++i) async16(&As[nxtA + aDst[i]], aSrc[i] + k1);
#pragma unroll
      for (int i = 0; i < 4; ++i) async16(&Bs[nxtB + bDst[i]], bSrc[i] + k1);
      asm volatile("s_waitcnt vmcnt(6)" ::: "memory");
    } else {
      asm volatile("s_waitcnt vmcnt(0)" ::: "memory");
    }
    __builtin_amdgcn_s_barrier();
    const int cA = cur * 4096, cB = cur * 8192;
#pragma unroll
    for (int s = 0; s < 2; ++s) {
      s16x8 a[2], b[4];
#pragma unroll
      for (int m = 0; m < 2; ++m) a[m] = *(const s16x8*)&As[cA + aOff[m][s]];
#pragma unroll
      for (int n = 0; n < 4; ++n) b[n] = *(const s16x8*)&Bs[cB + bOff[n][s]];
#pragma unroll
      for (int i = 0; i < 2; ++i)
#pragma unroll
        for (int j = 0; j < 4; ++j)
          acc[i][j] = __builtin_amdgcn_mfma_f32_16x16x32_bf16(a[i], b[j], acc[i][j], 0, 0, 0);
    }
    if (more) { __builtin_amdgcn_s_barrier(); cur ^= 1; }
  }

#pragma unroll
  for (int i = 0; i < 2; ++i)
#pragma unroll
    for (int q = 0; q < 4; ++q) {
      int r = wr * 32 + i * 16 + lhi * 4 + q;
      if (m0 + r < cntE) {
        int orow; float wgt;
        if (routed) {
          int d = dst[rowbase + m0 + r];
          orow = d >> 1;
          wgt = tw[d];
        } else {
          orow = m0 + r;
          wgt = 1.f;
        }
        float* orow_p = out + (size_t)orow * DIMSZ + n0 + wc * 64 + llo;
#pragma unroll
        for (int j = 0; j < 4; ++j)
          atomicAdd(&orow_p[j * 16], wgt * acc[i][j][q]);
      }
    }
}

extern "C" void kernel_launch(void* const* d_in, const int* in_sizes, int n_in,
                              void* d_out, int out_size, void* d_ws, size_t ws_size,
                              hipStream_t stream) {
  const float* x   = (const float*)d_in[0];
  const float* gw  = (const float*)d_in[1];
  const float* w1  = (const float*)d_in[2];
  const float* w3  = (const float*)d_in[3];
  const float* w2  = (const float*)d_in[4];
  const float* sw1 = (const float*)d_in[5];
  const float* sw3 = (const float*)d_in[6];
  const float* sw2 = (const float*)d_in[7];
  float* out = (float*)d_out;

  char* p = (char*)d_ws;
  auto alloc = [&](size_t bytes) {
    char* r = p;
    p += (bytes + 255) & ~(size_t)255;
    return r;
  };
  unsigned short* xb   = (unsigned short*)alloc((size_t)T_TOK * DIMSZ * 2);
  unsigned short* w1b  = (unsigned short*)alloc((size_t)NE * HIDSZ * DIMSZ * 2);
  unsigned short* w3b  = (unsigned short*)alloc((size_t)NE * HIDSZ * DIMSZ * 2);
  unsigned short* w2b  = (unsigned short*)alloc((size_t)NE * DIMSZ * HIDSZ * 2);
  unsigned short* sw1b = (unsigned short*)alloc((size_t)SHIDSZ * DIMSZ * 2);
  unsigned short* sw3b = (unsigned short*)alloc((size_t)SHIDSZ * DIMSZ * 2);
  unsigned short* sw2b = (unsigned short*)alloc((size_t)DIMSZ * SHIDSZ * 2);
  unsigned short* g_rt = (unsigned short*)alloc((size_t)2 * T_TOK * HIDSZ * 2);
  unsigned short* g_sh = (unsigned short*)alloc((size_t)T_TOK * SHIDSZ * 2);
  float* tw = (float*)alloc((size_t)2 * T_TOK * 4);
  int* ti   = (int*)alloc((size_t)2 * T_TOK * 4);
  int* tok  = (int*)alloc((size_t)2 * T_TOK * 4);
  int* dst  = (int*)alloc((size_t)2 * T_TOK * 4);
  int* meta = (int*)alloc(256);
  int* cnt = meta, *cursor = meta + 8, *base = meta + 16;

  auto cvt = [&](const float* s, unsigned short* d, size_t n) {
    int n4 = (int)(n / 4);
    cvt_bf16<<<(n4 + 255) / 256, 256, 0, stream>>>(s, d, n4);
  };
  cvt(x, xb, (size_t)T_TOK * DIMSZ);
  cvt(w1, w1b, (size_t)NE * HIDSZ * DIMSZ);
  cvt(w3, w3b, (size_t)NE * HIDSZ * DIMSZ);
  cvt(w2, w2b, (size_t)NE * DIMSZ * HIDSZ);
  cvt(sw1, sw1b, (size_t)SHIDSZ * DIMSZ);
  cvt(sw3, sw3b, (size_t)SHIDSZ * DIMSZ);
  cvt(sw2, sw2b, (size_t)DIMSZ * SHIDSZ);

  hipMemsetAsync(meta, 0, 64, stream);
  hipMemsetAsync(out, 0, (size_t)T_TOK * DIMSZ * 4, stream);
  gate_kernel<<<GATE_BLOCKS, 256, 0, stream>>>(x, gw, tw, ti, cnt);
  scan_kernel<<<1, 64, 0, stream>>>(cnt, base, cursor);
  scatter_kernel<<<T_TOK / 256, 256, 0, stream>>>(ti, cursor, tok, dst);

  // GEMM1: routed experts (x=0..511) + shared expert (x=512..575)
  gemm1_all<<<dim3((NE + 1) * (T_TOK / 128), SHIDSZ / 64), 256, 0, stream>>>(
      xb, tok, w1b, w3b, sw1b, sw3b, g_rt, g_sh, cnt, base);

  // GEMM2 + fused combine: routed (x=0..1023) + shared (x=1024..1151)
  gemm2_all<<<dim3(NE * (T_TOK / 64) + (T_TOK / 64), DIMSZ / 128), 256, 0, stream>>>(
      g_rt, g_sh, w2b, sw2b, cnt, base, dst, tw, out);
}